// Round 4
// baseline (192.868 us; speedup 1.0000x reference)
//
#include <hip/hip_runtime.h>
#include <math.h>

#define BB 32
#define LL 512
#define DD 32
#define KK 6
#define OO 192
#define DM 512

typedef __fp16 h2 __attribute__((ext_vector_type(2)));
union F2H { float f; h2 h; };
__device__ __forceinline__ float asF(h2 h) { F2H u; u.h = h; return u.f; }
__device__ __forceinline__ h2 asH(float f) { F2H u; u.f = f; return u.h; }

// LDS layout (float slots)
#define CSTR  520
#define XCOL  0                 // 7 cols x 520 (f32); overlaid later by f16 rows 512x4slots
#define YDMB  3648              // 192 x 4 slots (packed y f16) ; overlaid by DEN/NUM 2x768
#define MEDO  5184
#define STDO  5191
#define SAO   5198
#define SCO   5204
#define LDSF  5216              // 20.9 KB

// ---------------------------------------------------------------------------
// In-register bitonic sort of 512 floats across one wave (8 elems/lane).
// ---------------------------------------------------------------------------
__device__ __forceinline__ void sort512(float v[8], int lane) {
  #pragma unroll
  for (int k = 2; k <= 512; k <<= 1) {
    #pragma unroll
    for (int j = k >> 1; j > 0; j >>= 1) {
      if (j >= 8) {
        int jj = j >> 3;
        bool lower = (lane & jj) == 0;
        bool asc = ((lane << 3) & k) == 0;
        bool keepmin = (asc == lower);
        #pragma unroll
        for (int r = 0; r < 8; ++r) {
          float o = __shfl_xor(v[r], jj);
          v[r] = keepmin ? fminf(v[r], o) : fmaxf(v[r], o);
        }
      } else {
        #pragma unroll
        for (int r = 0; r < 8; ++r) {
          if ((r & j) == 0) {
            int r2 = r | j;
            bool asc = (((lane << 3) | r) & k) == 0;
            float a = v[r], b = v[r2];
            float lo = fminf(a, b), hi = fmaxf(a, b);
            v[r]  = asc ? lo : hi;
            v[r2] = asc ? hi : lo;
          }
        }
      }
    }
  }
}

// ---------------------------------------------------------------------------
// Fused: per-(b,d) order stats + affine map + attention + err + ymean.
// 256 threads = 4 waves; 1024 blocks; 20.9 KB LDS.
// ---------------------------------------------------------------------------
__global__ __launch_bounds__(256) void fused_kernel(
    const float* __restrict__ x, const float* __restrict__ x_date,
    const float* __restrict__ y_date,
    float* __restrict__ V, float* __restrict__ ymean, float* __restrict__ errt) {
  __shared__ float lds[LDSF];
  int bid = blockIdx.x, b = bid >> 5, d = bid & 31;
  int tid = threadIdx.x, lane = tid & 63, wv = tid >> 6;

  // ---- stage: rows t, t+256 of x_date -> f32 columns; x -> col 6 ----
  const float* xd = x_date + (size_t)b * LL * DD * KK + d * KK;
  const float* xp = x + (size_t)b * LL * DD + d;
  #pragma unroll
  for (int it = 0; it < 2; ++it) {
    int l = tid + it * 256;
    const float2* r2 = (const float2*)(xd + (size_t)l * (DD * KK));
    float2 a0 = r2[0], a1 = r2[1], a2 = r2[2];
    float xvv = xp[(size_t)l * DD];
    lds[XCOL + 0 * CSTR + l] = a0.x;
    lds[XCOL + 1 * CSTR + l] = a0.y;
    lds[XCOL + 2 * CSTR + l] = a1.x;
    lds[XCOL + 3 * CSTR + l] = a1.y;
    lds[XCOL + 4 * CSTR + l] = a2.x;
    lds[XCOL + 5 * CSTR + l] = a2.y;
    lds[XCOL + 6 * CSTR + l] = xvv;
  }
  __syncthreads();

  // ---- sort 7 sequences (2 passes of 4 waves) ----
  #pragma unroll
  for (int pass = 0; pass < 2; ++pass) {
    int s = pass * 4 + wv;
    if (s < 7) {
      float v[8];
      const float4* colp = (const float4*)&lds[XCOL + s * CSTR + lane * 8];
      float4 c0 = colp[0], c1 = colp[1];
      v[0]=c0.x; v[1]=c0.y; v[2]=c0.z; v[3]=c0.w;
      v[4]=c1.x; v[5]=c1.y; v[6]=c1.z; v[7]=c1.w;
      sort512(v, lane);
      float e127 = __shfl(v[7], 15);
      float e128 = __shfl(v[0], 16);
      float e255 = __shfl(v[7], 31);
      float e383 = __shfl(v[7], 47);
      float e384 = __shfl(v[0], 48);
      if (lane == 0) {
        float q25 = e127 + 0.75f * (e128 - e127);   // 0.25*(n-1)=127.75
        float q75 = e383 + 0.25f * (e384 - e383);   // 0.75*(n-1)=383.25
        lds[MEDO + s] = e255;                       // torch lower-median
        lds[STDO + s] = q75 - q25 + 1e-6f;
      }
    }
  }
  __syncthreads();

  if (tid < 6) {
    float a = lds[STDO + 6] / lds[STDO + tid];
    lds[SAO + tid] = a;
    lds[SCO + tid] = lds[MEDO + 6] - lds[MEDO + tid] * a;
  }
  __syncthreads();

  float ask[6], csk[6];
  #pragma unroll
  for (int k = 0; k < 6; ++k) { ask[k] = lds[SAO + k]; csk[k] = lds[SCO + k]; }

  const float PSC = 0.58912435f;   // (1/sqrt(6)) * log2(e)

  // ---- transform rows tid, tid+256 into regs (f16-packed, x-side prescaled) ----
  float4 packed[2];
  #pragma unroll
  for (int it = 0; it < 2; ++it) {
    int l = tid + it * 256;
    float m0 = ask[0]*lds[XCOL+0*CSTR+l] + csk[0];
    float m1 = ask[1]*lds[XCOL+1*CSTR+l] + csk[1];
    float m2 = ask[2]*lds[XCOL+2*CSTR+l] + csk[2];
    float m3 = ask[3]*lds[XCOL+3*CSTR+l] + csk[3];
    float m4 = ask[4]*lds[XCOL+4*CSTR+l] + csk[4];
    float m5 = ask[5]*lds[XCOL+5*CSTR+l] + csk[5];
    float xvv = lds[XCOL + 6*CSTR + l];
    errt[(size_t)bid * LL + l] = xvv - (m0+m1+m2+m3+m4+m5) * (1.0f/6.0f);
    packed[it].x = asF(__builtin_amdgcn_cvt_pkrtz(m0*PSC, m1*PSC));
    packed[it].y = asF(__builtin_amdgcn_cvt_pkrtz(m2*PSC, m3*PSC));
    packed[it].z = asF(__builtin_amdgcn_cvt_pkrtz(m4*PSC, m5*PSC));
    packed[it].w = asF(__builtin_amdgcn_cvt_pkrtz(xvv, 0.0f));
  }

  // ---- y staging (threads 0..191): map, ymean, pack (unscaled) ----
  float4 ypk; float ymv; bool doY = (tid < OO);
  if (doY) {
    const float2* yp = (const float2*)(y_date + ((size_t)b * OO + tid) * DD * KK + (size_t)d * KK);
    float2 y0 = yp[0], y1 = yp[1], y2 = yp[2];
    float q0 = ask[0]*y0.x + csk[0];
    float q1 = ask[1]*y0.y + csk[1];
    float q2 = ask[2]*y1.x + csk[2];
    float q3 = ask[3]*y1.y + csk[3];
    float q4 = ask[4]*y2.x + csk[4];
    float q5 = ask[5]*y2.y + csk[5];
    ymv = (q0+q1+q2+q3+q4+q5) * (1.0f/6.0f);
    ypk.x = asF(__builtin_amdgcn_cvt_pkrtz(q0, q1));
    ypk.y = asF(__builtin_amdgcn_cvt_pkrtz(q2, q3));
    ypk.z = asF(__builtin_amdgcn_cvt_pkrtz(q4, q5));
  }
  __syncthreads();   // all XCOL reads done; safe to overlay

  // ---- write f16 rows (overlay XCOL) + YDM; load yk frags ----
  *(float4*)&lds[tid * 4]         = packed[0];
  *(float4*)&lds[(tid + 256) * 4] = packed[1];
  if (doY) {
    ymean[(size_t)bid * OO + tid] = ymv;
    lds[YDMB + tid*4 + 0] = ypk.x;
    lds[YDMB + tid*4 + 1] = ypk.y;
    lds[YDMB + tid*4 + 2] = ypk.z;
  }
  __syncthreads();

  h2 yk[3][3];
  #pragma unroll
  for (int j = 0; j < 3; ++j) {
    int o = lane + 64 * j;
    yk[j][0] = asH(lds[YDMB + o*4 + 0]);
    yk[j][1] = asH(lds[YDMB + o*4 + 1]);
    yk[j][2] = asH(lds[YDMB + o*4 + 2]);
  }
  __syncthreads();   // yk loaded; DEN/NUM may overlay YDM after this

  // ---- attention: wave wv handles l in [wv*128, wv*128+128), 3 o's/lane ----
  float den[3] = {0.f,0.f,0.f}, num[3] = {0.f,0.f,0.f};
  int l0 = wv * 128;
  #pragma unroll 2
  for (int l = l0; l < l0 + 128; ++l) {
    float4 rw = *(const float4*)&lds[l * 4];
    h2 x01 = asH(rw.x), x23 = asH(rw.y), x45 = asH(rw.z);
    float xf = (float)(asH(rw.w).x);
    #pragma unroll
    for (int j = 0; j < 3; ++j) {
      float sc = __builtin_amdgcn_fdot2(x01, yk[j][0], 0.0f, false);
      sc = __builtin_amdgcn_fdot2(x23, yk[j][1], sc, false);
      sc = __builtin_amdgcn_fdot2(x45, yk[j][2], sc, false);
      float e = exp2f(sc);     // scale folded into x-side pack
      den[j] += e;
      num[j] += e * xf;
    }
  }
  #pragma unroll
  for (int j = 0; j < 3; ++j) {
    lds[YDMB + wv*192 + lane + 64*j]       = den[j];
    lds[YDMB + 768 + wv*192 + lane + 64*j] = num[j];
  }
  __syncthreads();
  if (tid < OO) {
    float dsum = lds[YDMB + tid] + lds[YDMB + 192 + tid]
               + lds[YDMB + 384 + tid] + lds[YDMB + 576 + tid];
    float nsum = lds[YDMB + 768 + tid] + lds[YDMB + 960 + tid]
               + lds[YDMB + 1152 + tid] + lds[YDMB + 1344 + tid];
    V[(size_t)bid * OO + tid] = nsum / dsum;
  }
}

// ---------------------------------------------------------------------------
// Gating MLP: 4 rows/block, 256 blocks, 256 threads, 2 m's per thread.
// esh transposed [4][512]: b128 broadcast reads serve 4 l's.
// ---------------------------------------------------------------------------
__global__ __launch_bounds__(256) void mlp_kernel(
    const float* __restrict__ errt, const float* __restrict__ w1,
    const float* __restrict__ b1, const float* __restrict__ w2,
    const float* __restrict__ b2, float* __restrict__ w0out) {
  int r0 = blockIdx.x * 4;
  int tid = threadIdx.x;
  __shared__ float esh[4 * LL];     // 8 KB

  const float4* src = (const float4*)(errt + (size_t)r0 * LL);
  ((float4*)esh)[tid]       = src[tid];
  ((float4*)esh)[tid + 256] = src[tid + 256];

  float2 bb = ((const float2*)b1)[tid];
  float2 acc[4];
  #pragma unroll
  for (int r = 0; r < 4; ++r) acc[r] = bb;
  __syncthreads();

  const float2* wp = (const float2*)w1 + tid;   // row l at wp[l*256]
  float2 wc[4];
  #pragma unroll
  for (int j = 0; j < 4; ++j) wc[j] = wp[j * 256];

  for (int g = 0; g < 128; ++g) {
    float4 e0 = *(const float4*)&esh[0*LL + g*4];
    float4 e1 = *(const float4*)&esh[1*LL + g*4];
    float4 e2 = *(const float4*)&esh[2*LL + g*4];
    float4 e3 = *(const float4*)&esh[3*LL + g*4];
    float2 wn[4] = {{0.f,0.f},{0.f,0.f},{0.f,0.f},{0.f,0.f}};
    if (g < 127) {
      #pragma unroll
      for (int j = 0; j < 4; ++j) wn[j] = wp[(g*4 + 4 + j) * 256];
    }
    #pragma unroll
    for (int j = 0; j < 4; ++j) {
      float ej0 = (j==0)?e0.x:(j==1)?e0.y:(j==2)?e0.z:e0.w;
      float ej1 = (j==0)?e1.x:(j==1)?e1.y:(j==2)?e1.z:e1.w;
      float ej2 = (j==0)?e2.x:(j==1)?e2.y:(j==2)?e2.z:e2.w;
      float ej3 = (j==0)?e3.x:(j==1)?e3.y:(j==2)?e3.z:e3.w;
      acc[0].x += ej0 * wc[j].x; acc[0].y += ej0 * wc[j].y;
      acc[1].x += ej1 * wc[j].x; acc[1].y += ej1 * wc[j].y;
      acc[2].x += ej2 * wc[j].x; acc[2].y += ej2 * wc[j].y;
      acc[3].x += ej3 * wc[j].x; acc[3].y += ej3 * wc[j].y;
    }
    #pragma unroll
    for (int j = 0; j < 4; ++j) wc[j] = wn[j];
  }

  float4 w2v = ((const float4*)w2)[tid];   // [m0c0,m0c1,m1c0,m1c1]
  float w2d0 = w2v.x - w2v.y, w2d1 = w2v.z - w2v.w;
  float p[4];
  #pragma unroll
  for (int r = 0; r < 4; ++r) {
    float h0 = acc[r].x, h1 = acc[r].y;
    float g0 = 0.5f * h0 * (1.0f + erff(h0 * 0.70710678f));
    float g1 = 0.5f * h1 * (1.0f + erff(h1 * 0.70710678f));
    p[r] = g0 * w2d0 + g1 * w2d1;
  }
  #pragma unroll
  for (int r = 0; r < 4; ++r)
    for (int off = 32; off > 0; off >>= 1)
      p[r] += __shfl_down(p[r], off);

  __shared__ float part[4][4];
  int wave = tid >> 6, lane = tid & 63;
  if (lane == 0) {
    #pragma unroll
    for (int r = 0; r < 4; ++r) part[wave][r] = p[r];
  }
  __syncthreads();
  if (tid < 4) {
    float ld = b2[0] - b2[1] + part[0][tid] + part[1][tid] + part[2][tid] + part[3][tid];
    w0out[r0 + tid] = 1.0f / (1.0f + expf(-ld));
  }
}

// ---------------------------------------------------------------------------
__global__ __launch_bounds__(256) void bnstats_kernel(
    const float* __restrict__ V, float* __restrict__ mu, float* __restrict__ rstd) {
  int d = blockIdx.x;
  int tid = threadIdx.x;
  float s = 0.0f, s2 = 0.0f;
  for (int idx = tid; idx < BB * OO; idx += 256) {
    int b = idx / OO, o = idx - b * OO;
    float v = V[((size_t)b * DD + d) * OO + o];
    s += v; s2 += v * v;
  }
  for (int off = 32; off > 0; off >>= 1) {
    s  += __shfl_down(s, off);
    s2 += __shfl_down(s2, off);
  }
  __shared__ float ps[4], ps2[4];
  int wave = tid >> 6, lane = tid & 63;
  if (lane == 0) { ps[wave] = s; ps2[wave] = s2; }
  __syncthreads();
  if (tid == 0) {
    float S = ps[0] + ps[1] + ps[2] + ps[3];
    float S2 = ps2[0] + ps2[1] + ps2[2] + ps2[3];
    const float inv = 1.0f / (BB * OO);
    float mean = S * inv;
    float var = S2 * inv - mean * mean;
    mu[d] = mean;
    rstd[d] = rsqrtf(var + 1e-5f);
  }
}

// ---------------------------------------------------------------------------
// Final fusion, threads mapped (b,d,o) so V/ymean reads coalesce.
// ---------------------------------------------------------------------------
__global__ __launch_bounds__(256) void final_kernel(
    const float* __restrict__ V, const float* __restrict__ ymean,
    const float* __restrict__ w0, const float* __restrict__ mu,
    const float* __restrict__ rstd, const float* __restrict__ gamma,
    const float* __restrict__ beta, float* __restrict__ out) {
  int idx = blockIdx.x * 256 + threadIdx.x;   // (b,d,o)
  int b = idx / (DD * OO);
  int rem = idx - b * (DD * OO);
  int d = rem / OO, o = rem - d * OO;
  int row = b * DD + d;
  float vv = V[idx];
  float ym = ymean[idx];
  float wq = w0[row];
  float y = (vv - mu[d]) * rstd[d] * gamma[d] + beta[d];
  out[(size_t)b * OO * DD + (size_t)o * DD + d] = ym * wq + y * (1.0f - wq);
}

// ---------------------------------------------------------------------------
extern "C" void kernel_launch(void* const* d_in, const int* in_sizes, int n_in,
                              void* d_out, int out_size, void* d_ws, size_t ws_size,
                              hipStream_t stream) {
  const float* x      = (const float*)d_in[0];
  const float* x_date = (const float*)d_in[1];
  const float* y_date = (const float*)d_in[2];
  const float* w1     = (const float*)d_in[3];
  const float* b1     = (const float*)d_in[4];
  const float* w2     = (const float*)d_in[5];
  const float* b2     = (const float*)d_in[6];
  const float* gamma  = (const float*)d_in[7];
  const float* beta   = (const float*)d_in[8];
  float* out = (float*)d_out;

  float* ws    = (float*)d_ws;
  float* V     = ws;                 // 196608 (B,D,O)
  float* ymean = ws + 196608;        // 196608 (B,D,O)
  float* errt  = ws + 393216;        // 524288 (B,D,L)
  float* w0    = ws + 917504;        // 1024   (B,D)
  float* mu    = ws + 918528;        // 32
  float* rstd  = ws + 918560;        // 32

  fused_kernel<<<BB * DD, 256, 0, stream>>>(x, x_date, y_date, V, ymean, errt);
  mlp_kernel<<<BB * DD / 4, 256, 0, stream>>>(errt, w1, b1, w2, b2, w0);
  bnstats_kernel<<<DD, 256, 0, stream>>>(V, mu, rstd);
  final_kernel<<<(BB * OO * DD) / 256, 256, 0, stream>>>(V, ymean, w0, mu, rstd,
                                                         gamma, beta, out);
}